// Round 8
// baseline (316.075 us; speedup 1.0000x reference)
//
#include <hip/hip_runtime.h>
#include <hip/hip_bf16.h>

// ---------------------------------------------------------------------------
// MultiheadAttention: x[2,2048,1024] fp32 -> out[2,2048,1024] fp32. H=16, D=64.
// Pipeline:
//   1) qkv_gemm : 128x128-tile LDS-staged bf16-MFMA GEMM (m93-style: 4 waves x
//                 4x4 frags, 16 MFMA per 8 ds_read_b128 per k-step) ->
//                 Q (pre-scaled by log2e/8), K [BH,S,D], Vt [BH,D,S] bf16.
//   2) attn     : transposed flash attention, unshifted base-2 softmax,
//                 SPLIT-K 2-way: block = 2 q-groups x 2 key-halves; partial
//                 (O^T, li) merge by pure addition via one LDS round-trip
//                 (exact: no max-shift to reconcile). 1024 blocks -> 50% occ.
//                 In-loop: no LDS, no barriers, no shuffles. XCD-swizzled.
//   3) out_gemm : 128x128-tile LDS-staged GEMM, fp32 out + bias.
// ws (32 MiB): [Q 8MiB][K 8MiB][Vt 8MiB][AO 8MiB]
// MFMA 16x16x32 bf16 layouts (m89/m91 verified):
//   A-frag: lane holds A[m=lane&15][k=(lane>>4)*8+j]
//   B-frag: lane holds B[k=(lane>>4)*8+j][n=lane&15]
//   C/D   : lane holds D[row=(lane>>4)*4+i][col=lane&15]
// Interleaved key-tiling (attn): QK^T m-row l16 -> key ((l16>>2)<<3)+(l16&3)
// (+4 tile B) => S^T C-layout == PV B-frag layout; zero-shuffle P transpose.
// ---------------------------------------------------------------------------

typedef __attribute__((ext_vector_type(8))) short bf16x8;
typedef __attribute__((ext_vector_type(4))) short bf16x4;
typedef __attribute__((ext_vector_type(4))) float f32x4;

#define MFMA16(a, b, c) __builtin_amdgcn_mfma_f32_16x16x32_bf16((a), (b), (c), 0, 0, 0)

#if __has_builtin(__builtin_amdgcn_exp2f)
#define EXP2F(x) __builtin_amdgcn_exp2f(x)
#else
#define EXP2F(x) exp2f(x)
#endif

static __device__ __forceinline__ unsigned short f2bf_bits(float v) {
    __hip_bfloat16 h = __float2bfloat16(v);
    return *reinterpret_cast<unsigned short*>(&h);
}

static __device__ __forceinline__ bf16x8 cvt8(const float* p) {
    const f32x4 a = reinterpret_cast<const f32x4*>(p)[0];
    const f32x4 b = reinterpret_cast<const f32x4*>(p)[1];
    bf16x8 r;
    r[0] = (short)f2bf_bits(a[0]); r[1] = (short)f2bf_bits(a[1]);
    r[2] = (short)f2bf_bits(a[2]); r[3] = (short)f2bf_bits(a[3]);
    r[4] = (short)f2bf_bits(b[0]); r[5] = (short)f2bf_bits(b[1]);
    r[6] = (short)f2bf_bits(b[2]); r[7] = (short)f2bf_bits(b[3]);
    return r;
}

__device__ __forceinline__ bf16x8 ldg8(const __hip_bfloat16* p) {
    return *reinterpret_cast<const bf16x8*>(p);
}

// ---------------------------------------------------------------------------
// Kernel 1: QKV projection, 128x128 tile. 4 waves in 2x2; each wave 64x64
// (4x4 MFMA frags). Q pre-scaled by (1/8)*log2(e).
// ---------------------------------------------------------------------------
__global__ __launch_bounds__(256)
void qkv_gemm(const float* __restrict__ x,
              const float* __restrict__ wqkv,
              const float* __restrict__ bqkv,
              __hip_bfloat16* __restrict__ Q,
              __hip_bfloat16* __restrict__ K,
              __hip_bfloat16* __restrict__ Vt) {
    __shared__ unsigned short As[128 * 40];
    __shared__ unsigned short Bs[128 * 40];

    const int tid  = threadIdx.x;
    const int lane = tid & 63;
    const int wv   = tid >> 6;
    const int quad = lane >> 4;
    const int l16  = lane & 15;
    const int wm   = wv >> 1;           // wave row (0..1)
    const int wn   = wv & 1;            // wave col (0..1)
    const int m0   = blockIdx.y * 128;
    const int n0   = blockIdx.x * 128;

    // staging: thread -> (row, 16-col half); 16 fp32 = 64B contiguous/thread
    const int sr = tid >> 1;            // 0..127
    const int sc = (tid & 1) * 16;      // 0,16
    const float* ag = x    + (size_t)(m0 + sr) * 1024 + sc;
    const float* bg = wqkv + (size_t)(n0 + sr) * 1024 + sc;
    unsigned short* aw = &As[sr * 40 + sc];
    unsigned short* bw = &Bs[sr * 40 + sc];

    f32x4 zv = {0.f, 0.f, 0.f, 0.f};
    f32x4 acc[4][4];
#pragma unroll
    for (int ii = 0; ii < 4; ++ii)
#pragma unroll
        for (int jj = 0; jj < 4; ++jj) acc[ii][jj] = zv;

    for (int k0 = 0; k0 < 1024; k0 += 32) {
        const bf16x8 av0 = cvt8(ag + k0), av1 = cvt8(ag + k0 + 8);
        const bf16x8 bv0 = cvt8(bg + k0), bv1 = cvt8(bg + k0 + 8);
        __syncthreads();
        reinterpret_cast<bf16x8*>(aw)[0] = av0;
        reinterpret_cast<bf16x8*>(aw)[1] = av1;
        reinterpret_cast<bf16x8*>(bw)[0] = bv0;
        reinterpret_cast<bf16x8*>(bw)[1] = bv1;
        __syncthreads();
        bf16x8 af[4], bf[4];
#pragma unroll
        for (int ii = 0; ii < 4; ++ii)
            af[ii] = *reinterpret_cast<const bf16x8*>(
                &As[(wm * 64 + ii * 16 + l16) * 40 + quad * 8]);
#pragma unroll
        for (int jj = 0; jj < 4; ++jj)
            bf[jj] = *reinterpret_cast<const bf16x8*>(
                &Bs[(wn * 64 + jj * 16 + l16) * 40 + quad * 8]);
#pragma unroll
        for (int ii = 0; ii < 4; ++ii)
#pragma unroll
            for (int jj = 0; jj < 4; ++jj)
                acc[ii][jj] = MFMA16(af[ii], bf[jj], acc[ii][jj]);
    }

    const float QSCALE = 0.18033688011f;   // 0.125 * log2(e)

#pragma unroll
    for (int jj = 0; jj < 4; ++jj) {
        const int n = n0 + wn * 64 + jj * 16 + l16;
        const float bias = bqkv[n];
        const int h = n / 192;
        const int r = n - h * 192;
        const int t = r >> 6;               // 0=Q 1=K 2=V
        const int d = r & 63;
#pragma unroll
        for (int ii = 0; ii < 4; ++ii) {
#pragma unroll
            for (int i = 0; i < 4; ++i) {
                const int m = m0 + wm * 64 + ii * 16 + quad * 4 + i;
                const int b = m >> 11;
                const int s = m & 2047;
                const int bh = b * 16 + h;
                float v = acc[ii][jj][i] + bias;
                if (t == 0) {
                    Q[((size_t)bh * 2048 + s) * 64 + d] = __float2bfloat16(v * QSCALE);
                } else if (t == 1) {
                    K[((size_t)bh * 2048 + s) * 64 + d] = __float2bfloat16(v);
                } else {
                    Vt[((size_t)bh * 64 + d) * 2048 + s] = __float2bfloat16(v);
                }
            }
        }
    }
}

// ---------------------------------------------------------------------------
// Kernel 2: transposed flash attention, split-K 2-way.
// 1024 blocks x 4 waves; wave = (q-group = wv>>1, key-half = wv&1);
// each wave: 32 queries x 1024 keys. Odd waves dump (Of, li) to LDS; even
// waves add (exact: unshifted softmax) and finalize.
// ---------------------------------------------------------------------------
__global__ __launch_bounds__(256)
void attn_kernel(const __hip_bfloat16* __restrict__ Q,
                 const __hip_bfloat16* __restrict__ K,
                 const __hip_bfloat16* __restrict__ Vt,
                 __hip_bfloat16* __restrict__ AO) {
    __shared__ float mbuf[2][64][34];    // [pair][lane][32 Of + 2 li]

    const int lane = threadIdx.x & 63;
    const int wv   = threadIdx.x >> 6;
    const int quad = lane >> 4;
    const int l16  = lane & 15;
    const int pair = wv >> 1;            // q-group in block
    const int half = wv & 1;             // key half

    const int blk = blockIdx.x;          // 0..1023
    const int xcd = blk & 7;
    const int sub = blk >> 3;            // 0..127
    const int bh  = xcd * 4 + (sub & 3); // same bh stays on one XCD
    const int qb  = sub >> 2;            // 0..31
    const int q0  = qb * 64 + pair * 32; // 32 queries per wave
    const int b   = bh >> 4;
    const int h   = bh & 15;

    const __hip_bfloat16* Qp = Q  + (size_t)bh * 131072;   // [S,D]
    const __hip_bfloat16* Kp = K  + (size_t)bh * 131072;   // [S,D]
    const __hip_bfloat16* Vp = Vt + (size_t)bh * 131072;   // [D,S]

    bf16x8 bQ[2][2];
#pragma unroll
    for (int t = 0; t < 2; ++t)
#pragma unroll
        for (int dh = 0; dh < 2; ++dh)
            bQ[t][dh] = ldg8(Qp + (size_t)(q0 + t * 16 + l16) * 64 + dh * 32 + quad * 8);

    const int krow = ((l16 >> 2) << 3) + (l16 & 3);

    f32x4 zv = {0.f, 0.f, 0.f, 0.f};
    f32x4 Of[2][4];
#pragma unroll
    for (int t = 0; t < 2; ++t)
#pragma unroll
        for (int jj = 0; jj < 4; ++jj) Of[t][jj] = zv;
    float li[2] = {0.f, 0.f};

    const int kt0 = half * 32;
    for (int kt = kt0; kt < kt0 + 32; ++kt) {
        const int key0 = kt * 32;

        bf16x8 aKA0 = ldg8(Kp + (size_t)(key0 + krow) * 64 + quad * 8);
        bf16x8 aKA1 = ldg8(Kp + (size_t)(key0 + krow) * 64 + 32 + quad * 8);
        bf16x8 aKB0 = ldg8(Kp + (size_t)(key0 + krow + 4) * 64 + quad * 8);
        bf16x8 aKB1 = ldg8(Kp + (size_t)(key0 + krow + 4) * 64 + 32 + quad * 8);
        bf16x8 aV[4];
#pragma unroll
        for (int jj = 0; jj < 4; ++jj)
            aV[jj] = ldg8(Vp + (size_t)(jj * 16 + l16) * 2048 + key0 + quad * 8);

        f32x4 sA[2], sB[2];
#pragma unroll
        for (int t = 0; t < 2; ++t) {
            sA[t] = zv; sB[t] = zv;
            sA[t] = MFMA16(aKA0, bQ[t][0], sA[t]);
            sA[t] = MFMA16(aKA1, bQ[t][1], sA[t]);
            sB[t] = MFMA16(aKB0, bQ[t][0], sB[t]);
            sB[t] = MFMA16(aKB1, bQ[t][1], sB[t]);
        }

#pragma unroll
        for (int t = 0; t < 2; ++t) {
            float pA[4], pB[4];
#pragma unroll
            for (int i = 0; i < 4; ++i) {
                pA[i] = EXP2F(sA[t][i]);
                pB[i] = EXP2F(sB[t][i]);
            }
            li[t] += ((pA[0] + pA[1]) + (pA[2] + pA[3]))
                   + ((pB[0] + pB[1]) + (pB[2] + pB[3]));

            bf16x8 bP;
            bP[0] = (short)f2bf_bits(pA[0]); bP[1] = (short)f2bf_bits(pA[1]);
            bP[2] = (short)f2bf_bits(pA[2]); bP[3] = (short)f2bf_bits(pA[3]);
            bP[4] = (short)f2bf_bits(pB[0]); bP[5] = (short)f2bf_bits(pB[1]);
            bP[6] = (short)f2bf_bits(pB[2]); bP[7] = (short)f2bf_bits(pB[3]);

#pragma unroll
            for (int jj = 0; jj < 4; ++jj)
                Of[t][jj] = MFMA16(aV[jj], bP, Of[t][jj]);
        }
    }

    // ---- split-K merge: odd waves publish, even waves add + finalize ------
    if (half) {
        float* dst = mbuf[pair][lane];
#pragma unroll
        for (int t = 0; t < 2; ++t) {
#pragma unroll
            for (int jj = 0; jj < 4; ++jj)
#pragma unroll
                for (int i = 0; i < 4; ++i)
                    dst[t * 16 + jj * 4 + i] = Of[t][jj][i];
            dst[32 + t] = li[t];
        }
    }
    __syncthreads();
    if (!half) {
        const float* src = mbuf[pair][lane];
#pragma unroll
        for (int t = 0; t < 2; ++t) {
#pragma unroll
            for (int jj = 0; jj < 4; ++jj)
#pragma unroll
                for (int i = 0; i < 4; ++i)
                    Of[t][jj][i] += src[t * 16 + jj * 4 + i];
            li[t] += src[32 + t];
        }

#pragma unroll
        for (int t = 0; t < 2; ++t) {
            li[t] += __shfl_xor(li[t], 16);
            li[t] += __shfl_xor(li[t], 32);
        }

#pragma unroll
        for (int t = 0; t < 2; ++t) {
            const float linv = 1.f / li[t];
            const int s = q0 + t * 16 + l16;
            __hip_bfloat16* aop = AO + (((size_t)b * 2048 + s) * 16 + h) * 64;
#pragma unroll
            for (int jj = 0; jj < 4; ++jj) {
                bf16x4 pk;
#pragma unroll
                for (int i = 0; i < 4; ++i)
                    pk[i] = (short)f2bf_bits(Of[t][jj][i] * linv);
                *reinterpret_cast<bf16x4*>(aop + jj * 16 + quad * 4) = pk;
            }
        }
    }
}

// ---------------------------------------------------------------------------
// Kernel 3: output projection, 128x128 tile (same structure as qkv), fp32 out.
// ---------------------------------------------------------------------------
__global__ __launch_bounds__(256)
void out_gemm(const __hip_bfloat16* __restrict__ A,
              const float* __restrict__ wo,
              const float* __restrict__ bo,
              float* __restrict__ out) {
    __shared__ unsigned short As[128 * 40];
    __shared__ unsigned short Bs[128 * 40];

    const int tid  = threadIdx.x;
    const int lane = tid & 63;
    const int wv   = tid >> 6;
    const int quad = lane >> 4;
    const int l16  = lane & 15;
    const int wm   = wv >> 1;
    const int wn   = wv & 1;
    const int m0   = blockIdx.y * 128;
    const int n0   = blockIdx.x * 128;

    const int sr = tid >> 1;
    const int sc = (tid & 1) * 16;
    const __hip_bfloat16* ag = A  + (size_t)(m0 + sr) * 1024 + sc;
    const float*          bg = wo + (size_t)(n0 + sr) * 1024 + sc;
    unsigned short* aw = &As[sr * 40 + sc];
    unsigned short* bw = &Bs[sr * 40 + sc];

    f32x4 zv = {0.f, 0.f, 0.f, 0.f};
    f32x4 acc[4][4];
#pragma unroll
    for (int ii = 0; ii < 4; ++ii)
#pragma unroll
        for (int jj = 0; jj < 4; ++jj) acc[ii][jj] = zv;

    for (int k0 = 0; k0 < 1024; k0 += 32) {
        const bf16x8 av0 = ldg8(ag + k0), av1 = ldg8(ag + k0 + 8);
        const bf16x8 bv0 = cvt8(bg + k0), bv1 = cvt8(bg + k0 + 8);
        __syncthreads();
        reinterpret_cast<bf16x8*>(aw)[0] = av0;
        reinterpret_cast<bf16x8*>(aw)[1] = av1;
        reinterpret_cast<bf16x8*>(bw)[0] = bv0;
        reinterpret_cast<bf16x8*>(bw)[1] = bv1;
        __syncthreads();
        bf16x8 af[4], bf[4];
#pragma unroll
        for (int ii = 0; ii < 4; ++ii)
            af[ii] = *reinterpret_cast<const bf16x8*>(
                &As[(wm * 64 + ii * 16 + l16) * 40 + quad * 8]);
#pragma unroll
        for (int jj = 0; jj < 4; ++jj)
            bf[jj] = *reinterpret_cast<const bf16x8*>(
                &Bs[(wn * 64 + jj * 16 + l16) * 40 + quad * 8]);
#pragma unroll
        for (int ii = 0; ii < 4; ++ii)
#pragma unroll
            for (int jj = 0; jj < 4; ++jj)
                acc[ii][jj] = MFMA16(af[ii], bf[jj], acc[ii][jj]);
    }

#pragma unroll
    for (int jj = 0; jj < 4; ++jj) {
        const int n = n0 + wn * 64 + jj * 16 + l16;
        const float bias = bo[n];
#pragma unroll
        for (int ii = 0; ii < 4; ++ii) {
#pragma unroll
            for (int i = 0; i < 4; ++i) {
                const int m = m0 + wm * 64 + ii * 16 + quad * 4 + i;
                out[(size_t)m * 1024 + n] = acc[ii][jj][i] + bias;
            }
        }
    }
}

// ---------------------------------------------------------------------------
extern "C" void kernel_launch(void* const* d_in, const int* in_sizes, int n_in,
                              void* d_out, int out_size, void* d_ws, size_t ws_size,
                              hipStream_t stream) {
    const float* x    = (const float*)d_in[0];
    const float* wqkv = (const float*)d_in[1];
    const float* bqkv = (const float*)d_in[2];
    const float* wo   = (const float*)d_in[3];
    const float* bo   = (const float*)d_in[4];
    float* out = (float*)d_out;

    __hip_bfloat16* ws = (__hip_bfloat16*)d_ws;
    __hip_bfloat16* Q  = ws;                       // [32,2048,64]  (x log2e/8)
    __hip_bfloat16* K  = ws + (size_t)4194304;
    __hip_bfloat16* Vt = ws + (size_t)8388608;
    __hip_bfloat16* AO = ws + (size_t)12582912;

    qkv_gemm<<<dim3(24, 32), 256, 0, stream>>>(x, wqkv, bqkv, Q, K, Vt);
    attn_kernel<<<dim3(1024), 256, 0, stream>>>(Q, K, Vt, AO);
    out_gemm<<<dim3(8, 32), 256, 0, stream>>>(AO, wo, bo, out);
}

// Round 9
// 214.393 us; speedup vs baseline: 1.4743x; 1.4743x over previous
//
#include <hip/hip_runtime.h>
#include <hip/hip_bf16.h>

// ---------------------------------------------------------------------------
// MultiheadAttention: x[2,2048,1024] fp32 -> out[2,2048,1024] fp32. H=16, D=64.
// All kernels bound by ~7 TB/s L2/L3 streaming (round-8 analysis) -> this
// round reduces bytes moved:
//   0) cast_x  : x fp32 -> xb bf16 (lives in AO slot, dead until attn)
//   1) qkv_gemm: 128x128 LDS-staged bf16 MFMA GEMM; A=xb bf16, B=wqkv fp32.
//               -> Q (pre-scaled log2e/8), K [BH,S,D], Vt [BH,D,S] bf16.
//   2) attn    : transposed flash attention (round-7 math: unshifted base-2
//               softmax, in-register P transpose) + cooperative LDS staging
//               of K/V tiles shared by 4 waves -> K/V traffic / 4.
//               K-tile stored sigma-permuted in two stride-40 half-tiles so
//               frag reads are conflict-free ds_read_b128 (round-5-verified
//               pattern). 128 q/block, 512 blocks, XCD-swizzled.
//   2b) cast_wo: wo fp32 -> wob bf16 into Q slot (dead after attn)
//   3) out_gemm: 128x128 LDS-staged GEMM, A=AO bf16, B=wob bf16, fp32 out.
// ws (32 MiB): [Q 8 | K 8 | Vt 8 | AO/xb 8]; wob overlays Q after attn.
// MFMA 16x16x32 bf16 layouts (m89/m91 verified):
//   A-frag: lane holds A[m=lane&15][k=(lane>>4)*8+j]
//   B-frag: lane holds B[k=(lane>>4)*8+j][n=lane&15]
//   C/D   : lane holds D[row=(lane>>4)*4+i][col=lane&15]
// Interleaved key-tiling (attn): S^T row l16 <-> key 8*(l16>>2)+(l16&3) (+4
// for tile B) => S^T C-layout == PV B-frag layout (zero-shuffle P transpose).
// sigma(key k=8a+b): row = 4a+b (b<4) | 16+4a+(b-4) (b>=4), applied at stage
// time so tile-A reads row l16, tile-B reads row 16+l16.
// ---------------------------------------------------------------------------

typedef __attribute__((ext_vector_type(8))) short bf16x8;
typedef __attribute__((ext_vector_type(4))) short bf16x4;
typedef __attribute__((ext_vector_type(4))) float f32x4;

#define MFMA16(a, b, c) __builtin_amdgcn_mfma_f32_16x16x32_bf16((a), (b), (c), 0, 0, 0)

#if __has_builtin(__builtin_amdgcn_exp2f)
#define EXP2F(x) __builtin_amdgcn_exp2f(x)
#else
#define EXP2F(x) exp2f(x)
#endif

static __device__ __forceinline__ unsigned short f2bf_bits(float v) {
    __hip_bfloat16 h = __float2bfloat16(v);
    return *reinterpret_cast<unsigned short*>(&h);
}

static __device__ __forceinline__ bf16x8 cvt8(const float* p) {
    const f32x4 a = reinterpret_cast<const f32x4*>(p)[0];
    const f32x4 b = reinterpret_cast<const f32x4*>(p)[1];
    bf16x8 r;
    r[0] = (short)f2bf_bits(a[0]); r[1] = (short)f2bf_bits(a[1]);
    r[2] = (short)f2bf_bits(a[2]); r[3] = (short)f2bf_bits(a[3]);
    r[4] = (short)f2bf_bits(b[0]); r[5] = (short)f2bf_bits(b[1]);
    r[6] = (short)f2bf_bits(b[2]); r[7] = (short)f2bf_bits(b[3]);
    return r;
}

__device__ __forceinline__ bf16x8 ldg8(const __hip_bfloat16* p) {
    return *reinterpret_cast<const bf16x8*>(p);
}

// ---------------------------------------------------------------------------
// Kernel 0: fp32 -> bf16 cast, 32 elems/thread.
// ---------------------------------------------------------------------------
__global__ __launch_bounds__(256)
void cast_f32_bf16(const float* __restrict__ src, __hip_bfloat16* __restrict__ dst) {
    const size_t base = ((size_t)blockIdx.x * 256 + threadIdx.x) * 32;
#pragma unroll
    for (int i = 0; i < 4; ++i)
        *reinterpret_cast<bf16x8*>(dst + base + i * 8) = cvt8(src + base + i * 8);
}

// ---------------------------------------------------------------------------
// Kernel 1: QKV projection, 128x128 tile, A = xb (bf16), B = wqkv (fp32).
// Q pre-scaled by (1/8)*log2(e).
// ---------------------------------------------------------------------------
__global__ __launch_bounds__(256)
void qkv_gemm(const __hip_bfloat16* __restrict__ xb,
              const float* __restrict__ wqkv,
              const float* __restrict__ bqkv,
              __hip_bfloat16* __restrict__ Q,
              __hip_bfloat16* __restrict__ K,
              __hip_bfloat16* __restrict__ Vt) {
    __shared__ unsigned short As[128 * 40];
    __shared__ unsigned short Bs[128 * 40];

    const int tid  = threadIdx.x;
    const int lane = tid & 63;
    const int wv   = tid >> 6;
    const int quad = lane >> 4;
    const int l16  = lane & 15;
    const int wm   = wv >> 1;
    const int wn   = wv & 1;
    const int m0   = blockIdx.y * 128;
    const int n0   = blockIdx.x * 128;

    const int sr = tid >> 1;            // 0..127
    const int sc = (tid & 1) * 16;      // 0,16
    const __hip_bfloat16* ag = xb + (size_t)(m0 + sr) * 1024 + sc;
    const float*          bg = wqkv + (size_t)(n0 + sr) * 1024 + sc;
    unsigned short* aw = &As[sr * 40 + sc];
    unsigned short* bw = &Bs[sr * 40 + sc];

    f32x4 zv = {0.f, 0.f, 0.f, 0.f};
    f32x4 acc[4][4];
#pragma unroll
    for (int ii = 0; ii < 4; ++ii)
#pragma unroll
        for (int jj = 0; jj < 4; ++jj) acc[ii][jj] = zv;

    for (int k0 = 0; k0 < 1024; k0 += 32) {
        const bf16x8 av0 = ldg8(ag + k0), av1 = ldg8(ag + k0 + 8);
        const bf16x8 bv0 = cvt8(bg + k0), bv1 = cvt8(bg + k0 + 8);
        __syncthreads();
        reinterpret_cast<bf16x8*>(aw)[0] = av0;
        reinterpret_cast<bf16x8*>(aw)[1] = av1;
        reinterpret_cast<bf16x8*>(bw)[0] = bv0;
        reinterpret_cast<bf16x8*>(bw)[1] = bv1;
        __syncthreads();
        bf16x8 af[4], bf[4];
#pragma unroll
        for (int ii = 0; ii < 4; ++ii)
            af[ii] = *reinterpret_cast<const bf16x8*>(
                &As[(wm * 64 + ii * 16 + l16) * 40 + quad * 8]);
#pragma unroll
        for (int jj = 0; jj < 4; ++jj)
            bf[jj] = *reinterpret_cast<const bf16x8*>(
                &Bs[(wn * 64 + jj * 16 + l16) * 40 + quad * 8]);
#pragma unroll
        for (int ii = 0; ii < 4; ++ii)
#pragma unroll
            for (int jj = 0; jj < 4; ++jj)
                acc[ii][jj] = MFMA16(af[ii], bf[jj], acc[ii][jj]);
    }

    const float QSCALE = 0.18033688011f;   // 0.125 * log2(e)

#pragma unroll
    for (int jj = 0; jj < 4; ++jj) {
        const int n = n0 + wn * 64 + jj * 16 + l16;
        const float bias = bqkv[n];
        const int h = n / 192;
        const int r = n - h * 192;
        const int t = r >> 6;               // 0=Q 1=K 2=V
        const int d = r & 63;
#pragma unroll
        for (int ii = 0; ii < 4; ++ii) {
#pragma unroll
            for (int i = 0; i < 4; ++i) {
                const int m = m0 + wm * 64 + ii * 16 + quad * 4 + i;
                const int b = m >> 11;
                const int s = m & 2047;
                const int bh = b * 16 + h;
                float v = acc[ii][jj][i] + bias;
                if (t == 0) {
                    Q[((size_t)bh * 2048 + s) * 64 + d] = __float2bfloat16(v * QSCALE);
                } else if (t == 1) {
                    K[((size_t)bh * 2048 + s) * 64 + d] = __float2bfloat16(v);
                } else {
                    Vt[((size_t)bh * 64 + d) * 2048 + s] = __float2bfloat16(v);
                }
            }
        }
    }
}

// ---------------------------------------------------------------------------
// Kernel 2: transposed flash attention with cooperative K/V LDS staging.
// 512 blocks x 4 waves; block owns 128 queries of one (b,h); 32 keys/iter
// staged once per block, shared by all 4 waves.
// ---------------------------------------------------------------------------
__global__ __launch_bounds__(256)
void attn_kernel(const __hip_bfloat16* __restrict__ Q,
                 const __hip_bfloat16* __restrict__ K,
                 const __hip_bfloat16* __restrict__ Vt,
                 __hip_bfloat16* __restrict__ AO) {
    __shared__ unsigned short Ks0[32 * 40];   // K d=[0,32), sigma-permuted rows
    __shared__ unsigned short Ks1[32 * 40];   // K d=[32,64)
    __shared__ unsigned short Vs[64 * 40];    // V^T [d][key]

    const int tid  = threadIdx.x;
    const int lane = tid & 63;
    const int wv   = tid >> 6;
    const int quad = lane >> 4;
    const int l16  = lane & 15;

    const int blk = blockIdx.x;          // 0..511
    const int xcd = blk & 7;
    const int sub = blk >> 3;            // 0..63
    const int bh  = xcd * 4 + (sub & 3); // same bh stays on one XCD
    const int qb  = sub >> 2;            // 0..15
    const int q0  = qb * 128 + wv * 32;  // 32 queries per wave
    const int b   = bh >> 4;
    const int h   = bh & 15;

    const __hip_bfloat16* Qp = Q  + (size_t)bh * 131072;   // [S,D]
    const __hip_bfloat16* Kp = K  + (size_t)bh * 131072;   // [S,D]
    const __hip_bfloat16* Vp = Vt + (size_t)bh * 131072;   // [D,S]

    bf16x8 bQ[2][2];
#pragma unroll
    for (int t = 0; t < 2; ++t)
#pragma unroll
        for (int dh = 0; dh < 2; ++dh)
            bQ[t][dh] = ldg8(Qp + (size_t)(q0 + t * 16 + l16) * 64 + dh * 32 + quad * 8);

    // staging: K: thread -> key row kr (0..31), 8-elem col kc (0..56)
    const int kr = tid >> 3;
    const int kc = (tid & 7) * 8;
    const int kb = kr & 7;
    const int sig = (kb < 4) ? ((kr >> 3) * 4 + kb) : (16 + (kr >> 3) * 4 + (kb - 4));
    unsigned short* kw = (kc < 32) ? &Ks0[sig * 40 + kc] : &Ks1[sig * 40 + (kc - 32)];
    // V: thread -> d row vr (0..63), 8-elem key col vc (0..24)
    const int vr = tid >> 2;
    const int vc = (tid & 3) * 8;
    unsigned short* vw = &Vs[vr * 40 + vc];

    f32x4 zv = {0.f, 0.f, 0.f, 0.f};
    f32x4 Of[2][4];
#pragma unroll
    for (int t = 0; t < 2; ++t)
#pragma unroll
        for (int jj = 0; jj < 4; ++jj) Of[t][jj] = zv;
    float li[2] = {0.f, 0.f};

    for (int kt = 0; kt < 64; ++kt) {
        const int key0 = kt * 32;

        const bf16x8 gk = ldg8(Kp + (size_t)(key0 + kr) * 64 + kc);
        const bf16x8 gv = ldg8(Vp + (size_t)vr * 2048 + key0 + vc);
        __syncthreads();                 // prev iter's LDS reads done
        *reinterpret_cast<bf16x8*>(kw) = gk;
        *reinterpret_cast<bf16x8*>(vw) = gv;
        __syncthreads();

        const bf16x8 aKA0 = *reinterpret_cast<const bf16x8*>(&Ks0[l16 * 40 + quad * 8]);
        const bf16x8 aKA1 = *reinterpret_cast<const bf16x8*>(&Ks1[l16 * 40 + quad * 8]);
        const bf16x8 aKB0 = *reinterpret_cast<const bf16x8*>(&Ks0[(16 + l16) * 40 + quad * 8]);
        const bf16x8 aKB1 = *reinterpret_cast<const bf16x8*>(&Ks1[(16 + l16) * 40 + quad * 8]);
        bf16x8 aV[4];
#pragma unroll
        for (int jj = 0; jj < 4; ++jj)
            aV[jj] = *reinterpret_cast<const bf16x8*>(&Vs[(jj * 16 + l16) * 40 + quad * 8]);

        f32x4 sA[2], sB[2];
#pragma unroll
        for (int t = 0; t < 2; ++t) {
            sA[t] = zv; sB[t] = zv;
            sA[t] = MFMA16(aKA0, bQ[t][0], sA[t]);
            sA[t] = MFMA16(aKA1, bQ[t][1], sA[t]);
            sB[t] = MFMA16(aKB0, bQ[t][0], sB[t]);
            sB[t] = MFMA16(aKB1, bQ[t][1], sB[t]);
        }

#pragma unroll
        for (int t = 0; t < 2; ++t) {
            float pA[4], pB[4];
#pragma unroll
            for (int i = 0; i < 4; ++i) {
                pA[i] = EXP2F(sA[t][i]);
                pB[i] = EXP2F(sB[t][i]);
            }
            li[t] += ((pA[0] + pA[1]) + (pA[2] + pA[3]))
                   + ((pB[0] + pB[1]) + (pB[2] + pB[3]));

            bf16x8 bP;
            bP[0] = (short)f2bf_bits(pA[0]); bP[1] = (short)f2bf_bits(pA[1]);
            bP[2] = (short)f2bf_bits(pA[2]); bP[3] = (short)f2bf_bits(pA[3]);
            bP[4] = (short)f2bf_bits(pB[0]); bP[5] = (short)f2bf_bits(pB[1]);
            bP[6] = (short)f2bf_bits(pB[2]); bP[7] = (short)f2bf_bits(pB[3]);

#pragma unroll
            for (int jj = 0; jj < 4; ++jj)
                Of[t][jj] = MFMA16(aV[jj], bP, Of[t][jj]);
        }
    }

#pragma unroll
    for (int t = 0; t < 2; ++t) {
        li[t] += __shfl_xor(li[t], 16);
        li[t] += __shfl_xor(li[t], 32);
    }

#pragma unroll
    for (int t = 0; t < 2; ++t) {
        const float linv = 1.f / li[t];
        const int s = q0 + t * 16 + l16;
        __hip_bfloat16* aop = AO + (((size_t)b * 2048 + s) * 16 + h) * 64;
#pragma unroll
        for (int jj = 0; jj < 4; ++jj) {
            bf16x4 pk;
#pragma unroll
            for (int i = 0; i < 4; ++i)
                pk[i] = (short)f2bf_bits(Of[t][jj][i] * linv);
            *reinterpret_cast<bf16x4*>(aop + jj * 16 + quad * 4) = pk;
        }
    }
}

// ---------------------------------------------------------------------------
// Kernel 3: output projection, 128x128 tile, A = AO bf16, B = wob bf16.
// ---------------------------------------------------------------------------
__global__ __launch_bounds__(256)
void out_gemm(const __hip_bfloat16* __restrict__ A,
              const __hip_bfloat16* __restrict__ wob,
              const float* __restrict__ bo,
              float* __restrict__ out) {
    __shared__ unsigned short As[128 * 40];
    __shared__ unsigned short Bs[128 * 40];

    const int tid  = threadIdx.x;
    const int lane = tid & 63;
    const int wv   = tid >> 6;
    const int quad = lane >> 4;
    const int l16  = lane & 15;
    const int wm   = wv >> 1;
    const int wn   = wv & 1;
    const int m0   = blockIdx.y * 128;
    const int n0   = blockIdx.x * 128;

    const int sr = tid >> 1;
    const int sc = (tid & 1) * 16;
    const __hip_bfloat16* ag = A   + (size_t)(m0 + sr) * 1024 + sc;
    const __hip_bfloat16* bg = wob + (size_t)(n0 + sr) * 1024 + sc;
    unsigned short* aw = &As[sr * 40 + sc];
    unsigned short* bw = &Bs[sr * 40 + sc];

    f32x4 zv = {0.f, 0.f, 0.f, 0.f};
    f32x4 acc[4][4];
#pragma unroll
    for (int ii = 0; ii < 4; ++ii)
#pragma unroll
        for (int jj = 0; jj < 4; ++jj) acc[ii][jj] = zv;

    for (int k0 = 0; k0 < 1024; k0 += 32) {
        const bf16x8 av0 = ldg8(ag + k0), av1 = ldg8(ag + k0 + 8);
        const bf16x8 bv0 = ldg8(bg + k0), bv1 = ldg8(bg + k0 + 8);
        __syncthreads();
        reinterpret_cast<bf16x8*>(aw)[0] = av0;
        reinterpret_cast<bf16x8*>(aw)[1] = av1;
        reinterpret_cast<bf16x8*>(bw)[0] = bv0;
        reinterpret_cast<bf16x8*>(bw)[1] = bv1;
        __syncthreads();
        bf16x8 af[4], bf[4];
#pragma unroll
        for (int ii = 0; ii < 4; ++ii)
            af[ii] = *reinterpret_cast<const bf16x8*>(
                &As[(wm * 64 + ii * 16 + l16) * 40 + quad * 8]);
#pragma unroll
        for (int jj = 0; jj < 4; ++jj)
            bf[jj] = *reinterpret_cast<const bf16x8*>(
                &Bs[(wn * 64 + jj * 16 + l16) * 40 + quad * 8]);
#pragma unroll
        for (int ii = 0; ii < 4; ++ii)
#pragma unroll
            for (int jj = 0; jj < 4; ++jj)
                acc[ii][jj] = MFMA16(af[ii], bf[jj], acc[ii][jj]);
    }

#pragma unroll
    for (int jj = 0; jj < 4; ++jj) {
        const int n = n0 + wn * 64 + jj * 16 + l16;
        const float bias = bo[n];
#pragma unroll
        for (int ii = 0; ii < 4; ++ii) {
#pragma unroll
            for (int i = 0; i < 4; ++i) {
                const int m = m0 + wm * 64 + ii * 16 + quad * 4 + i;
                out[(size_t)m * 1024 + n] = acc[ii][jj][i] + bias;
            }
        }
    }
}

// ---------------------------------------------------------------------------
extern "C" void kernel_launch(void* const* d_in, const int* in_sizes, int n_in,
                              void* d_out, int out_size, void* d_ws, size_t ws_size,
                              hipStream_t stream) {
    const float* x    = (const float*)d_in[0];
    const float* wqkv = (const float*)d_in[1];
    const float* bqkv = (const float*)d_in[2];
    const float* wo   = (const float*)d_in[3];
    const float* bo   = (const float*)d_in[4];
    float* out = (float*)d_out;

    __hip_bfloat16* ws = (__hip_bfloat16*)d_ws;
    __hip_bfloat16* Q   = ws;                      // [32,2048,64] (x log2e/8)
    __hip_bfloat16* K   = ws + (size_t)4194304;
    __hip_bfloat16* Vt  = ws + (size_t)8388608;
    __hip_bfloat16* AO  = ws + (size_t)12582912;   // also xb before attn
    __hip_bfloat16* xb  = AO;                      // 4M elems (8 MiB) overlay
    __hip_bfloat16* wob = Q;                       // 1M elems overlay after attn

    // 0) x fp32 -> bf16 (4M elems, 32/thread)
    cast_f32_bf16<<<dim3(512), 256, 0, stream>>>(x, xb);
    // 1) QKV projection: M=4096, N=3072, K=1024
    qkv_gemm<<<dim3(24, 32), 256, 0, stream>>>(xb, wqkv, bqkv, Q, K, Vt);
    // 2) attention: 32 bh x 16 q-blocks = 512 blocks
    attn_kernel<<<dim3(512), 256, 0, stream>>>(Q, K, Vt, AO);
    // 2b) wo fp32 -> bf16 into dead Q slot (1M elems)
    cast_f32_bf16<<<dim3(128), 256, 0, stream>>>(wo, wob);
    // 3) output projection: M=4096, N=1024, K=1024
    out_gemm<<<dim3(8, 32), 256, 0, stream>>>(AO, wob, bo, out);
}